// Round 15
// baseline (225.997 us; speedup 1.0000x reference)
//
#include <hip/hip_runtime.h>

#define N_ 8192
#define INF_ 512
#define OUTF_ 256
#define KVSPLIT 8
#define BK 32
#define BQ 128
#define NTILES (N_ / KVSPLIT / BK)   // 32

typedef float f32x4 __attribute__((ext_vector_type(4)));
typedef float f32x16 __attribute__((ext_vector_type(16)));
typedef __bf16 bf16x8 __attribute__((ext_vector_type(8)));

__device__ __forceinline__ unsigned short f2bf(float f) {
  union { float f; unsigned u; } v; v.f = f;
  unsigned r = v.u + 0x7fffu + ((v.u >> 16) & 1u);
  return (unsigned short)(r >> 16);
}
__device__ __forceinline__ float bf2f(unsigned short u) {
  union { unsigned u; float f; } v; v.u = ((unsigned)u) << 16;
  return v.f;
}

// ---------------------------------------------------------------------------
// Kernel 0: prep (tiny): W -> WT (bf16, [col][k]).
// ---------------------------------------------------------------------------
__global__ __launch_bounds__(256) void k_prep(
    const float* __restrict__ W, unsigned short* __restrict__ WT)
{
  int idx = blockIdx.x * 256 + threadIdx.x;   // 131072 threads
  int c = idx & (OUTF_ - 1);
  int k = idx >> 8;
  WT[c * INF_ + k] = f2bf(W[k * OUTF_ + c]);
}

// ---------------------------------------------------------------------------
// Kernel 1: h = x @ W via bf16 MFMA, hi/lo split built IN-REGISTER from f32 x.
// 512 blocks (2/CU) of 32 rows x 128 cols. No LDS.
// ---------------------------------------------------------------------------
__global__ __launch_bounds__(256) void k_gemm_h(
    const float* __restrict__ x, const unsigned short* __restrict__ WT,
    unsigned short* __restrict__ hK, unsigned short* __restrict__ hT)
{
  const int tid = threadIdx.x;
  const int w = tid >> 6, l = tid & 63, g = l >> 4, li = l & 15;
  const int r0 = blockIdx.x * 32 + (w & 1) * 16;
  const int c0 = blockIdx.y * 128 + (w >> 1) * 64;

  f32x4 acc[4];
  const f32x4 z4 = {0.f, 0.f, 0.f, 0.f};
#pragma unroll
  for (int n = 0; n < 4; ++n) acc[n] = z4;

  const float* xp = x + (size_t)(r0 + li) * INF_ + g * 8;
  const unsigned short* wt = WT + (size_t)(c0 + li) * INF_ + g * 8;

#pragma unroll 4
  for (int kc = 0; kc < 16; ++kc) {
    float4 v0 = *(const float4*)(xp + kc * 32);
    float4 v1 = *(const float4*)(xp + kc * 32 + 4);
    float f[8] = {v0.x, v0.y, v0.z, v0.w, v1.x, v1.y, v1.z, v1.w};
    union { unsigned short s[8]; bf16x8 v; } uh, ul;
#pragma unroll
    for (int j = 0; j < 8; ++j) {
      uh.s[j] = f2bf(f[j]);
      ul.s[j] = f2bf(f[j] - bf2f(uh.s[j]));
    }
    bf16x8 Ah = uh.v, Al = ul.v;
#pragma unroll
    for (int n = 0; n < 4; ++n) {
      bf16x8 Bn = *(const bf16x8*)(wt + (size_t)n * 16 * INF_ + kc * 32);
      acc[n] = __builtin_amdgcn_mfma_f32_16x16x32_bf16(Ah, Bn, acc[n], 0, 0, 0);
      acc[n] = __builtin_amdgcn_mfma_f32_16x16x32_bf16(Al, Bn, acc[n], 0, 0, 0);
    }
  }
#pragma unroll
  for (int n = 0; n < 4; ++n)
#pragma unroll
    for (int s = 0; s < 4; ++s) {
      unsigned short b = f2bf(acc[n][s]);
      int row = r0 + 4 * g + s;
      int col = c0 + n * 16 + li;
      hK[(size_t)row * OUTF_ + col] = b;
      hT[(size_t)col * N_ + row] = b;
    }
}

// ---------------------------------------------------------------------------
// Kernel 2: fused masked attention (v11/v13 pipeline; steady loop unroll-2
// so buffer roles are compile-time). 32x32x16 MFMA, software-pipelined:
// per tile t: Pf(t) from carried pk -> ONE merged MFMA region
// { PV(t) || QK(t+1) } -> softmax(t+1) -> barrier.
// 4 waves x 32 q-rows, BK=32, 64 KB LDS -> 2 blocks/CU.
// ---------------------------------------------------------------------------
__global__ __launch_bounds__(256, 2) void k_attn(
    const unsigned short* __restrict__ hK, const unsigned short* __restrict__ hT,
    const int* __restrict__ adj, const float* __restrict__ a,
    unsigned short* __restrict__ Opart, float* __restrict__ lsum)
{
  __shared__ __align__(16) unsigned char smem[65536];
  unsigned char* KA = smem;            // K buf 0: [32 kv][256 k], chunk^=(row&7)
  unsigned char* VA = smem + 16384;    // V buf 0: [256 d][32 kv], chunk^=((d^(d>>2))&3)
  unsigned char* KB = smem + 32768;    // K buf 1
  unsigned char* VB = smem + 49152;    // V buf 1

  const int tid = threadIdx.x;
  const int w = tid >> 6, l = tid & 63;
  const int q32 = l & 31;
  const int hi = l >> 5;
  const int bid = blockIdx.x;
  const int split = bid & 7;           // XCD-aligned KV split
  const int qblk = (bid >> 3) * BQ;
  const int qrw = qblk + w * 32;
  const int jb = split * (N_ / KVSPLIT);
  const float SCALE = 0.18033688011112042f;  // log2(e)/8 (folded into Qf)

  // staging source offsets (16B chunks), LDS dest linear
  int offK[4], offV[4];
#pragma unroll
  for (int p = 0; p < 4; ++p) {
    int ch = tid + p * 256;
    int rK = ch >> 5, cK = ch & 31;
    offK[p] = rK * OUTF_ + ((cK ^ (rK & 7)) * 8);
    int dV = ch >> 2, cV = ch & 3;
    offV[p] = dV * N_ + ((cV ^ ((dV ^ (dV >> 2)) & 3)) * 8);
  }
  // K read addressing: row = q32 (kv), chunk (2kt+hi) ^ (q32&7)
  const int kbase = q32 * 512;
  const int ehk = (hi ^ (q32 & 7)) << 4;
  // V read addressing
  const int sv = (q32 ^ (q32 >> 2)) & 3;
  const int c0v = (sv & 2) | (hi ^ (sv & 1));
  const int voff0 = q32 * 64 + (c0v << 4);

  // adj: lane-private row qrw+q32, kv cols 4*hi + {0,8,16,24} (+ t*32)
  const int* adjp = adj + (size_t)(qrw + q32) * N_ + jb + 4 * hi;

  // Q fragments (SCALE folded): q-row = qrw+q32, k = kt*16 + 8*hi + j
  bf16x8 Qf[16];
  {
    const unsigned short* hp = hK + (size_t)(qrw + q32) * OUTF_;
#pragma unroll
    for (int kt = 0; kt < 16; ++kt) {
      const int off = kt * 16 + 8 * hi;
      bf16x8 hv = *(const bf16x8*)(hp + off);
      float4 a0 = *(const float4*)(a + off);
      float4 a1 = *(const float4*)(a + off + 4);
      bf16x8 q;
      q[0] = (__bf16)((float)hv[0] * (a0.x * SCALE));
      q[1] = (__bf16)((float)hv[1] * (a0.y * SCALE));
      q[2] = (__bf16)((float)hv[2] * (a0.z * SCALE));
      q[3] = (__bf16)((float)hv[3] * (a0.w * SCALE));
      q[4] = (__bf16)((float)hv[4] * (a1.x * SCALE));
      q[5] = (__bf16)((float)hv[5] * (a1.y * SCALE));
      q[6] = (__bf16)((float)hv[6] * (a1.z * SCALE));
      q[7] = (__bf16)((float)hv[7] * (a1.w * SCALE));
      Qf[kt] = q;
    }
  }

  f32x16 O[8];
#pragma unroll
  for (int dt = 0; dt < 8; ++dt)
#pragma unroll
    for (int r = 0; r < 16; ++r) O[dt][r] = 0.f;
  float lp2[2] = {0.f, 0.f};

#define STAGEK(tt, Kd) do { \
    const unsigned short* _hk = hK + (size_t)(jb + (tt) * BK) * OUTF_; \
    _Pragma("unroll") \
    for (int p = 0; p < 4; ++p) \
      __builtin_amdgcn_global_load_lds( \
        (const __attribute__((address_space(1))) void*)(_hk + offK[p]), \
        (__attribute__((address_space(3))) void*)((Kd) + (p * 256 + w * 64) * 16), 16, 0, 0); \
  } while (0)
#define STAGEV(tt, Vd) do { \
    const unsigned short* _ht = hT + (jb + (tt) * BK); \
    _Pragma("unroll") \
    for (int p = 0; p < 4; ++p) \
      __builtin_amdgcn_global_load_lds( \
        (const __attribute__((address_space(1))) void*)(_ht + offV[p]), \
        (__attribute__((address_space(3))) void*)((Vd) + (p * 256 + w * 64) * 16), 16, 0, 0); \
  } while (0)

// softmax for tile s: St + ad -> pk, lp2.  mask[r] = ad[r>>2][r&3]
#define SOFTMAX() do { \
    _Pragma("unroll") \
    for (int i = 0; i < 8; ++i) { \
      int m0, m1; \
      const int4 av = ad[i >> 1]; \
      if ((i & 1) == 0) { m0 = av.x; m1 = av.y; } \
      else             { m0 = av.z; m1 = av.w; } \
      float e0 = exp2f(St[2 * i]); \
      float e1 = exp2f(St[2 * i + 1]); \
      float v0 = m0 ? e0 : 0.f; \
      float v1 = m1 ? e1 : 0.f; \
      lp2[i & 1] += v0 + v1; \
      asm("v_cvt_pk_bf16_f32 %0, %1, %2" : "=v"(pk[i]) : "v"(v0), "v"(v1)); \
    } \
  } while (0)

#define MKPF() do { \
    _Pragma("unroll") \
    for (int tt = 0; tt < 2; ++tt) { \
      unsigned u0 = pk[4 * tt],     u2 = pk[4 * tt + 2]; \
      unsigned u1 = pk[4 * tt + 1], u3 = pk[4 * tt + 3]; \
      asm("v_permlane32_swap_b32 %0, %1" : "+v"(u0), "+v"(u2)); \
      asm("v_permlane32_swap_b32 %0, %1" : "+v"(u1), "+v"(u3)); \
      union { unsigned u[4]; bf16x8 v; } pu; \
      pu.u[0] = u0; pu.u[1] = u1; pu.u[2] = u2; pu.u[3] = u3; \
      Pf[tt] = pu.v; \
    } \
  } while (0)

// one steady-loop body with compile-time buffer roles
#define TILEBODY(t, Kstage, Knext, Vstage, Vcur) do { \
    if ((t) + 2 < NTILES) STAGEK((t) + 2, Kstage); \
    STAGEV((t) + 1, Vstage); \
    _Pragma("unroll") \
    for (int i = 0; i < 4; ++i) ad[i] = *(const int4*)(adjp + ((t) + 1) * 32 + i * 8); \
    MKPF(); \
    _Pragma("unroll") \
    for (int r = 0; r < 16; ++r) St[r] = 0.f; \
    { \
      const unsigned char* kb = (Knext) + kbase; \
      __builtin_amdgcn_s_setprio(1); \
      _Pragma("unroll") \
      for (int s = 0; s < 8; ++s) { \
        bf16x8 kf0 = *(const bf16x8*)(kb + (((2 * s) << 5) ^ ehk)); \
        bf16x8 kf1 = *(const bf16x8*)(kb + (((2 * s + 1) << 5) ^ ehk)); \
        bf16x8 v0  = *(const bf16x8*)((Vcur) + s * 2048 + voff0); \
        bf16x8 v1  = *(const bf16x8*)((Vcur) + s * 2048 + (voff0 ^ 32)); \
        St   = __builtin_amdgcn_mfma_f32_32x32x16_bf16(kf0, Qf[2 * s], St, 0, 0, 0); \
        O[s] = __builtin_amdgcn_mfma_f32_32x32x16_bf16(Pf[0], v0, O[s], 0, 0, 0); \
        St   = __builtin_amdgcn_mfma_f32_32x32x16_bf16(kf1, Qf[2 * s + 1], St, 0, 0, 0); \
        O[s] = __builtin_amdgcn_mfma_f32_32x32x16_bf16(Pf[1], v1, O[s], 0, 0, 0); \
      } \
      __builtin_amdgcn_s_setprio(0); \
    } \
    SOFTMAX(); \
    __syncthreads(); \
  } while (0)

  int4 ad[4];
  unsigned pk[8];
  bf16x8 Pf[2];
  f32x16 St;

  // ---- prologue: K(0)/V(0) staged, QK(0), softmax(0) -> pk
  STAGEK(0, KA);
  STAGEV(0, VA);
#pragma unroll
  for (int i = 0; i < 4; ++i) ad[i] = *(const int4*)(adjp + i * 8);
  __syncthreads();
  STAGEK(1, KB);
  {
#pragma unroll
    for (int r = 0; r < 16; ++r) St[r] = 0.f;
    const unsigned char* kb = KA + kbase;
#pragma unroll
    for (int kt = 0; kt < 16; ++kt) {
      bf16x8 kf = *(const bf16x8*)(kb + ((kt << 5) ^ ehk));
      St = __builtin_amdgcn_mfma_f32_32x32x16_bf16(kf, Qf[kt], St, 0, 0, 0);
    }
    SOFTMAX();
  }
  __syncthreads();   // K(1) landed

  // ---- steady loop, unrolled x2: even t then odd t (NTILES-1 = 31 bodies)
#pragma unroll 1
  for (int tp = 0; tp < (NTILES - 1) / 2; ++tp) {
    const int t0 = 2 * tp;
    TILEBODY(t0,     KA, KB, VB, VA);   // t even: stage K->KA, QK from KB, stage V->VB, PV from VA
    TILEBODY(t0 + 1, KB, KA, VA, VB);   // t odd : roles swapped
  }
  // last steady body: t = NTILES-2 (even, since NTILES=32)
  TILEBODY(NTILES - 2, KA, KB, VB, VA);

  // ---- final tile: PV only (V(31) in VB)
  MKPF();
  {
    const unsigned char* Vlast = VB;
    __builtin_amdgcn_s_setprio(1);
#pragma unroll
    for (int s = 0; s < 8; ++s) {
      bf16x8 v0 = *(const bf16x8*)(Vlast + s * 2048 + voff0);
      bf16x8 v1 = *(const bf16x8*)(Vlast + s * 2048 + (voff0 ^ 32));
      O[s] = __builtin_amdgcn_mfma_f32_32x32x16_bf16(Pf[0], v0, O[s], 0, 0, 0);
      O[s] = __builtin_amdgcn_mfma_f32_32x32x16_bf16(Pf[1], v1, O[s], 0, 0, 0);
    }
    __builtin_amdgcn_s_setprio(0);
  }
#undef STAGEK
#undef STAGEV
#undef SOFTMAX
#undef MKPF
#undef TILEBODY

  // ---- epilogue
  {
    float lpv = lp2[0] + lp2[1];
    float lfull = lpv + __shfl_xor(lpv, 32);
    if (l < 32)
      lsum[(size_t)split * N_ + qrw + q32] = lfull;
  }
  const size_t ob = (size_t)split * N_ * OUTF_;
#pragma unroll
  for (int dt = 0; dt < 8; ++dt)
#pragma unroll
    for (int r = 0; r < 16; ++r) {
      int q = (r & 3) + 8 * (r >> 2) + 4 * hi;
      Opart[ob + (size_t)(qrw + q) * OUTF_ + dt * 32 + q32] = f2bf(O[dt][r]);
    }
}

// ---------------------------------------------------------------------------
// Kernel 3: combine splits (plain sums), normalize, ELU.
// ---------------------------------------------------------------------------
__global__ __launch_bounds__(256) void k_combine(
    const unsigned short* __restrict__ Opart, const float* __restrict__ lsum,
    float* __restrict__ out)
{
  int idx = blockIdx.x * 256 + threadIdx.x;   // N*64 threads
  int row = idx >> 6;
  int c = (idx & 63) * 4;
  float L = 0.f, a0 = 0.f, a1 = 0.f, a2 = 0.f, a3 = 0.f;
#pragma unroll
  for (int s = 0; s < KVSPLIT; ++s) {
    L += lsum[(size_t)s * N_ + row];
    uint2 o = *(const uint2*)(Opart + ((size_t)s * N_ + row) * OUTF_ + c);
    a0 += bf2f((unsigned short)(o.x & 0xffff));
    a1 += bf2f((unsigned short)(o.x >> 16));
    a2 += bf2f((unsigned short)(o.y & 0xffff));
    a3 += bf2f((unsigned short)(o.y >> 16));
  }
  float inv = 1.f / L;
  float r0 = a0 * inv, r1 = a1 * inv, r2 = a2 * inv, r3 = a3 * inv;
  float4 r;
  r.x = r0 > 0.f ? r0 : expm1f(r0);
  r.y = r1 > 0.f ? r1 : expm1f(r1);
  r.z = r2 > 0.f ? r2 : expm1f(r2);
  r.w = r3 > 0.f ? r3 : expm1f(r3);
  *(float4*)(out + (size_t)row * OUTF_ + c) = r;
}

// ---------------------------------------------------------------------------
extern "C" void kernel_launch(void* const* d_in, const int* in_sizes, int n_in,
                              void* d_out, int out_size, void* d_ws, size_t ws_size,
                              hipStream_t stream) {
  const float* x  = (const float*)d_in[0];
  const int* adj  = (const int*)d_in[1];
  const float* W  = (const float*)d_in[2];
  const float* a  = (const float*)d_in[3];
  float* out = (float*)d_out;
  char* ws = (char*)d_ws;

  unsigned short* hK = (unsigned short*)(ws);                             // 0..4MB
  unsigned short* hT = (unsigned short*)(ws + (size_t)4 * 1024 * 1024);   // 4..8MB
  unsigned short* WT = (unsigned short*)(ws + (size_t)8 * 1024 * 1024);   // 8..9MB
  float* lsum = (float*)(ws + (size_t)9 * 1024 * 1024);                   // 9..10MB
  unsigned short* Opart = (unsigned short*)(ws + (size_t)10 * 1024 * 1024); // 10..42MB

  k_prep<<<(INF_ * OUTF_) / 256, 256, 0, stream>>>(W, WT);
  dim3 g1(N_ / 32, 2);
  k_gemm_h<<<g1, 256, 0, stream>>>(x, WT, hK, hT);
  k_attn<<<(N_ / BQ) * KVSPLIT, 256, 0, stream>>>(hK, hT, adj, a, Opart, lsum);
  k_combine<<<(N_ * 64) / 256, 256, 0, stream>>>(Opart, lsum, out);
}

// Round 16
// 149.797 us; speedup vs baseline: 1.5087x; 1.5087x over previous
//
#include <hip/hip_runtime.h>

#define N_ 8192
#define INF_ 512
#define OUTF_ 256
#define KVSPLIT 8
#define BK 32
#define BQ 128
#define NTILES (N_ / KVSPLIT / BK)   // 32

typedef float f32x4 __attribute__((ext_vector_type(4)));
typedef float f32x16 __attribute__((ext_vector_type(16)));
typedef __bf16 bf16x8 __attribute__((ext_vector_type(8)));

__device__ __forceinline__ unsigned short f2bf(float f) {
  union { float f; unsigned u; } v; v.f = f;
  unsigned r = v.u + 0x7fffu + ((v.u >> 16) & 1u);
  return (unsigned short)(r >> 16);
}
__device__ __forceinline__ float bf2f(unsigned short u) {
  union { unsigned u; float f; } v; v.u = ((unsigned)u) << 16;
  return v.f;
}

// ---------------------------------------------------------------------------
// Kernel 0: prep (tiny): W -> WT (bf16, [col][k]).
// ---------------------------------------------------------------------------
__global__ __launch_bounds__(256) void k_prep(
    const float* __restrict__ W, unsigned short* __restrict__ WT)
{
  int idx = blockIdx.x * 256 + threadIdx.x;   // 131072 threads
  int c = idx & (OUTF_ - 1);
  int k = idx >> 8;
  WT[c * INF_ + k] = f2bf(W[k * OUTF_ + c]);
}

// ---------------------------------------------------------------------------
// Kernel 1: h = x @ W via bf16 MFMA, hi/lo split built IN-REGISTER from f32 x
// (bit-identical to a prep-pass split; same bytes/lane as bf16 hi+lo reads).
// 512 blocks (2/CU) of 32 rows x 128 cols. No LDS.
// ---------------------------------------------------------------------------
__global__ __launch_bounds__(256) void k_gemm_h(
    const float* __restrict__ x, const unsigned short* __restrict__ WT,
    unsigned short* __restrict__ hK, unsigned short* __restrict__ hT)
{
  const int tid = threadIdx.x;
  const int w = tid >> 6, l = tid & 63, g = l >> 4, li = l & 15;
  const int r0 = blockIdx.x * 32 + (w & 1) * 16;
  const int c0 = blockIdx.y * 128 + (w >> 1) * 64;

  f32x4 acc[4];
  const f32x4 z4 = {0.f, 0.f, 0.f, 0.f};
#pragma unroll
  for (int n = 0; n < 4; ++n) acc[n] = z4;

  const float* xp = x + (size_t)(r0 + li) * INF_ + g * 8;
  const unsigned short* wt = WT + (size_t)(c0 + li) * INF_ + g * 8;

#pragma unroll 4
  for (int kc = 0; kc < 16; ++kc) {
    float4 v0 = *(const float4*)(xp + kc * 32);
    float4 v1 = *(const float4*)(xp + kc * 32 + 4);
    float f[8] = {v0.x, v0.y, v0.z, v0.w, v1.x, v1.y, v1.z, v1.w};
    union { unsigned short s[8]; bf16x8 v; } uh, ul;
#pragma unroll
    for (int j = 0; j < 8; ++j) {
      uh.s[j] = f2bf(f[j]);
      ul.s[j] = f2bf(f[j] - bf2f(uh.s[j]));
    }
    bf16x8 Ah = uh.v, Al = ul.v;
#pragma unroll
    for (int n = 0; n < 4; ++n) {
      bf16x8 Bn = *(const bf16x8*)(wt + (size_t)n * 16 * INF_ + kc * 32);
      acc[n] = __builtin_amdgcn_mfma_f32_16x16x32_bf16(Ah, Bn, acc[n], 0, 0, 0);
      acc[n] = __builtin_amdgcn_mfma_f32_16x16x32_bf16(Al, Bn, acc[n], 0, 0, 0);
    }
  }
#pragma unroll
  for (int n = 0; n < 4; ++n)
#pragma unroll
    for (int s = 0; s < 4; ++s) {
      unsigned short b = f2bf(acc[n][s]);
      int row = r0 + 4 * g + s;
      int col = c0 + n * 16 + li;
      hK[(size_t)row * OUTF_ + col] = b;
      hT[(size_t)col * N_ + row] = b;
    }
}

// ---------------------------------------------------------------------------
// Kernel 2: fused masked attention (v14 state — best known).
// 32x32x16 MFMA, software-pipelined: per tile t: Pf(t) from carried pk ->
// ONE merged MFMA region { PV(t) || QK(t+1) } -> softmax(t+1) -> barrier.
// K read 1-ahead / staged 2-ahead; V read current / staged 1-ahead.
// Compact runtime-ternary buffer roles (unroll-2 regressed: I-cache).
// 4 waves x 32 q-rows, BK=32, 64 KB LDS -> 2 blocks/CU.
// ---------------------------------------------------------------------------
__global__ __launch_bounds__(256, 2) void k_attn(
    const unsigned short* __restrict__ hK, const unsigned short* __restrict__ hT,
    const int* __restrict__ adj, const float* __restrict__ a,
    unsigned short* __restrict__ Opart, float* __restrict__ lsum)
{
  __shared__ __align__(16) unsigned char smem[65536];
  unsigned char* KA = smem;            // K buf 0: [32 kv][256 k], chunk^=(row&7)
  unsigned char* VA = smem + 16384;    // V buf 0: [256 d][32 kv], chunk^=((d^(d>>2))&3)
  unsigned char* KB = smem + 32768;    // K buf 1
  unsigned char* VB = smem + 49152;    // V buf 1

  const int tid = threadIdx.x;
  const int w = tid >> 6, l = tid & 63;
  const int q32 = l & 31;
  const int hi = l >> 5;
  const int bid = blockIdx.x;
  const int split = bid & 7;           // XCD-aligned KV split
  const int qblk = (bid >> 3) * BQ;
  const int qrw = qblk + w * 32;
  const int jb = split * (N_ / KVSPLIT);
  const float SCALE = 0.18033688011112042f;  // log2(e)/8 (folded into Qf)

  // staging source offsets (16B chunks), LDS dest linear
  int offK[4], offV[4];
#pragma unroll
  for (int p = 0; p < 4; ++p) {
    int ch = tid + p * 256;
    int rK = ch >> 5, cK = ch & 31;
    offK[p] = rK * OUTF_ + ((cK ^ (rK & 7)) * 8);
    int dV = ch >> 2, cV = ch & 3;
    offV[p] = dV * N_ + ((cV ^ ((dV ^ (dV >> 2)) & 3)) * 8);
  }
  // K read addressing: row = q32 (kv), chunk (2kt+hi) ^ (q32&7)
  const int kbase = q32 * 512;
  const int ehk = (hi ^ (q32 & 7)) << 4;
  // V read addressing
  const int sv = (q32 ^ (q32 >> 2)) & 3;
  const int c0v = (sv & 2) | (hi ^ (sv & 1));
  const int voff0 = q32 * 64 + (c0v << 4);

  // adj: lane-private row qrw+q32, kv cols 4*hi + {0,8,16,24} (+ t*32)
  const int* adjp = adj + (size_t)(qrw + q32) * N_ + jb + 4 * hi;

  // Q fragments (SCALE folded): q-row = qrw+q32, k = kt*16 + 8*hi + j
  bf16x8 Qf[16];
  {
    const unsigned short* hp = hK + (size_t)(qrw + q32) * OUTF_;
#pragma unroll
    for (int kt = 0; kt < 16; ++kt) {
      const int off = kt * 16 + 8 * hi;
      bf16x8 hv = *(const bf16x8*)(hp + off);
      float4 a0 = *(const float4*)(a + off);
      float4 a1 = *(const float4*)(a + off + 4);
      bf16x8 q;
      q[0] = (__bf16)((float)hv[0] * (a0.x * SCALE));
      q[1] = (__bf16)((float)hv[1] * (a0.y * SCALE));
      q[2] = (__bf16)((float)hv[2] * (a0.z * SCALE));
      q[3] = (__bf16)((float)hv[3] * (a0.w * SCALE));
      q[4] = (__bf16)((float)hv[4] * (a1.x * SCALE));
      q[5] = (__bf16)((float)hv[5] * (a1.y * SCALE));
      q[6] = (__bf16)((float)hv[6] * (a1.z * SCALE));
      q[7] = (__bf16)((float)hv[7] * (a1.w * SCALE));
      Qf[kt] = q;
    }
  }

  f32x16 O[8];
#pragma unroll
  for (int dt = 0; dt < 8; ++dt)
#pragma unroll
    for (int r = 0; r < 16; ++r) O[dt][r] = 0.f;
  float lp2[2] = {0.f, 0.f};

#define STAGEK(tt, Kd) do { \
    const unsigned short* _hk = hK + (size_t)(jb + (tt) * BK) * OUTF_; \
    _Pragma("unroll") \
    for (int p = 0; p < 4; ++p) \
      __builtin_amdgcn_global_load_lds( \
        (const __attribute__((address_space(1))) void*)(_hk + offK[p]), \
        (__attribute__((address_space(3))) void*)((Kd) + (p * 256 + w * 64) * 16), 16, 0, 0); \
  } while (0)
#define STAGEV(tt, Vd) do { \
    const unsigned short* _ht = hT + (jb + (tt) * BK); \
    _Pragma("unroll") \
    for (int p = 0; p < 4; ++p) \
      __builtin_amdgcn_global_load_lds( \
        (const __attribute__((address_space(1))) void*)(_ht + offV[p]), \
        (__attribute__((address_space(3))) void*)((Vd) + (p * 256 + w * 64) * 16), 16, 0, 0); \
  } while (0)

// softmax for tile s: St + ad -> pk, lp2.  mask[r] = ad[r>>2][r&3]
#define SOFTMAX() do { \
    _Pragma("unroll") \
    for (int i = 0; i < 8; ++i) { \
      int m0, m1; \
      const int4 av = ad[i >> 1]; \
      if ((i & 1) == 0) { m0 = av.x; m1 = av.y; } \
      else             { m0 = av.z; m1 = av.w; } \
      float e0 = exp2f(St[2 * i]); \
      float e1 = exp2f(St[2 * i + 1]); \
      float v0 = m0 ? e0 : 0.f; \
      float v1 = m1 ? e1 : 0.f; \
      lp2[i & 1] += v0 + v1; \
      asm("v_cvt_pk_bf16_f32 %0, %1, %2" : "=v"(pk[i]) : "v"(v0), "v"(v1)); \
    } \
  } while (0)

#define MKPF() do { \
    _Pragma("unroll") \
    for (int tt = 0; tt < 2; ++tt) { \
      unsigned u0 = pk[4 * tt],     u2 = pk[4 * tt + 2]; \
      unsigned u1 = pk[4 * tt + 1], u3 = pk[4 * tt + 3]; \
      asm("v_permlane32_swap_b32 %0, %1" : "+v"(u0), "+v"(u2)); \
      asm("v_permlane32_swap_b32 %0, %1" : "+v"(u1), "+v"(u3)); \
      union { unsigned u[4]; bf16x8 v; } pu; \
      pu.u[0] = u0; pu.u[1] = u1; pu.u[2] = u2; pu.u[3] = u3; \
      Pf[tt] = pu.v; \
    } \
  } while (0)

  int4 ad[4];
  unsigned pk[8];
  bf16x8 Pf[2];
  f32x16 St;

  // ---- prologue: K(0)/V(0) staged, QK(0), softmax(0) -> pk
  STAGEK(0, KA);
  STAGEV(0, VA);
#pragma unroll
  for (int i = 0; i < 4; ++i) ad[i] = *(const int4*)(adjp + i * 8);
  __syncthreads();
  STAGEK(1, KB);
  {
#pragma unroll
    for (int r = 0; r < 16; ++r) St[r] = 0.f;
    const unsigned char* kb = KA + kbase;
#pragma unroll
    for (int kt = 0; kt < 16; ++kt) {
      bf16x8 kf = *(const bf16x8*)(kb + ((kt << 5) ^ ehk));
      St = __builtin_amdgcn_mfma_f32_32x32x16_bf16(kf, Qf[kt], St, 0, 0, 0);
    }
    SOFTMAX();
  }
  __syncthreads();   // K(1) landed

  // ---- steady loop: tile t does PV(t) || QK(t+1), then softmax(t+1)
#pragma unroll 1
  for (int t = 0; t < NTILES - 1; ++t) {
    // buffer roles this iteration
    unsigned char* Kstage = (t & 1) ? KB : KA;        // receives K(t+2)
    const unsigned char* Knext = (t & 1) ? KA : KB;   // holds K(t+1)
    unsigned char* Vstage = (t & 1) ? VA : VB;        // receives V(t+1)
    const unsigned char* Vcur  = (t & 1) ? VB : VA;   // holds V(t)

    if (t + 2 < NTILES) STAGEK(t + 2, Kstage);
    STAGEV(t + 1, Vstage);
#pragma unroll
    for (int i = 0; i < 4; ++i) ad[i] = *(const int4*)(adjp + (t + 1) * 32 + i * 8);

    MKPF();   // Pf(t) from carried pk; pk dies here

#pragma unroll
    for (int r = 0; r < 16; ++r) St[r] = 0.f;
    {
      const unsigned char* kb = Knext + kbase;
      __builtin_amdgcn_s_setprio(1);
#pragma unroll
      for (int s = 0; s < 8; ++s) {
        bf16x8 kf0 = *(const bf16x8*)(kb + (((2 * s) << 5) ^ ehk));
        bf16x8 kf1 = *(const bf16x8*)(kb + (((2 * s + 1) << 5) ^ ehk));
        bf16x8 v0  = *(const bf16x8*)(Vcur + s * 2048 + voff0);
        bf16x8 v1  = *(const bf16x8*)(Vcur + s * 2048 + (voff0 ^ 32));
        St   = __builtin_amdgcn_mfma_f32_32x32x16_bf16(kf0, Qf[2 * s], St, 0, 0, 0);
        O[s] = __builtin_amdgcn_mfma_f32_32x32x16_bf16(Pf[0], v0, O[s], 0, 0, 0);
        St   = __builtin_amdgcn_mfma_f32_32x32x16_bf16(kf1, Qf[2 * s + 1], St, 0, 0, 0);
        O[s] = __builtin_amdgcn_mfma_f32_32x32x16_bf16(Pf[1], v1, O[s], 0, 0, 0);
      }
      __builtin_amdgcn_s_setprio(0);
    }
    SOFTMAX();        // pk(t+1) carried out

    __syncthreads();  // staging (K(t+2), V(t+1)) landed; buffers safe to flip
  }

  // ---- final tile: PV only
  MKPF();
  {
    const unsigned char* Vlast = ((NTILES - 1) & 1) ? VB : VA;
    __builtin_amdgcn_s_setprio(1);
#pragma unroll
    for (int s = 0; s < 8; ++s) {
      bf16x8 v0 = *(const bf16x8*)(Vlast + s * 2048 + voff0);
      bf16x8 v1 = *(const bf16x8*)(Vlast + s * 2048 + (voff0 ^ 32));
      O[s] = __builtin_amdgcn_mfma_f32_32x32x16_bf16(Pf[0], v0, O[s], 0, 0, 0);
      O[s] = __builtin_amdgcn_mfma_f32_32x32x16_bf16(Pf[1], v1, O[s], 0, 0, 0);
    }
    __builtin_amdgcn_s_setprio(0);
  }
#undef STAGEK
#undef STAGEV
#undef SOFTMAX
#undef MKPF

  // ---- epilogue
  {
    float lpv = lp2[0] + lp2[1];
    float lfull = lpv + __shfl_xor(lpv, 32);
    if (l < 32)
      lsum[(size_t)split * N_ + qrw + q32] = lfull;
  }
  const size_t ob = (size_t)split * N_ * OUTF_;
#pragma unroll
  for (int dt = 0; dt < 8; ++dt)
#pragma unroll
    for (int r = 0; r < 16; ++r) {
      int q = (r & 3) + 8 * (r >> 2) + 4 * hi;
      Opart[ob + (size_t)(qrw + q) * OUTF_ + dt * 32 + q32] = f2bf(O[dt][r]);
    }
}

// ---------------------------------------------------------------------------
// Kernel 3: combine splits (plain sums), normalize, ELU.
// ---------------------------------------------------------------------------
__global__ __launch_bounds__(256) void k_combine(
    const unsigned short* __restrict__ Opart, const float* __restrict__ lsum,
    float* __restrict__ out)
{
  int idx = blockIdx.x * 256 + threadIdx.x;   // N*64 threads
  int row = idx >> 6;
  int c = (idx & 63) * 4;
  float L = 0.f, a0 = 0.f, a1 = 0.f, a2 = 0.f, a3 = 0.f;
#pragma unroll
  for (int s = 0; s < KVSPLIT; ++s) {
    L += lsum[(size_t)s * N_ + row];
    uint2 o = *(const uint2*)(Opart + ((size_t)s * N_ + row) * OUTF_ + c);
    a0 += bf2f((unsigned short)(o.x & 0xffff));
    a1 += bf2f((unsigned short)(o.x >> 16));
    a2 += bf2f((unsigned short)(o.y & 0xffff));
    a3 += bf2f((unsigned short)(o.y >> 16));
  }
  float inv = 1.f / L;
  float r0 = a0 * inv, r1 = a1 * inv, r2 = a2 * inv, r3 = a3 * inv;
  float4 r;
  r.x = r0 > 0.f ? r0 : expm1f(r0);
  r.y = r1 > 0.f ? r1 : expm1f(r1);
  r.z = r2 > 0.f ? r2 : expm1f(r2);
  r.w = r3 > 0.f ? r3 : expm1f(r3);
  *(float4*)(out + (size_t)row * OUTF_ + c) = r;
}

// ---------------------------------------------------------------------------
extern "C" void kernel_launch(void* const* d_in, const int* in_sizes, int n_in,
                              void* d_out, int out_size, void* d_ws, size_t ws_size,
                              hipStream_t stream) {
  const float* x  = (const float*)d_in[0];
  const int* adj  = (const int*)d_in[1];
  const float* W  = (const float*)d_in[2];
  const float* a  = (const float*)d_in[3];
  float* out = (float*)d_out;
  char* ws = (char*)d_ws;

  unsigned short* hK = (unsigned short*)(ws);                             // 0..4MB
  unsigned short* hT = (unsigned short*)(ws + (size_t)4 * 1024 * 1024);   // 4..8MB
  unsigned short* WT = (unsigned short*)(ws + (size_t)8 * 1024 * 1024);   // 8..9MB
  float* lsum = (float*)(ws + (size_t)9 * 1024 * 1024);                   // 9..10MB
  unsigned short* Opart = (unsigned short*)(ws + (size_t)10 * 1024 * 1024); // 10..42MB

  k_prep<<<(INF_ * OUTF_) / 256, 256, 0, stream>>>(W, WT);
  dim3 g1(N_ / 32, 2);
  k_gemm_h<<<g1, 256, 0, stream>>>(x, WT, hK, hT);
  k_attn<<<(N_ / BQ) * KVSPLIT, 256, 0, stream>>>(hK, hT, adj, a, Opart, lsum);
  k_combine<<<(N_ * 64) / 256, 256, 0, stream>>>(Opart, lsum, out);
}